// Round 2
// baseline (732.564 us; speedup 1.0000x reference)
//
#include <hip/hip_runtime.h>

#define NSUB 4096
#define DIM 64
#define NROW 8192
#define KTOP 20
#define LM 24          // fast-pass candidate list length (margin over 20)

typedef unsigned long long u64;

// -------------------------------------------------------------------------
// K1: V[k] = emb[k] @ w[k] + b[k], f64 accumulate from f32 inputs.
//   which==0 -> V1d [4][4096][64] f64 + V1s f32 (row-major)
//   which==1 -> V2d [4][4096][64] f64 (row-major, for refine)
//               + V2Ts [4][64][4096] f32 (transposed, for fast pass)
// grid 512, block 256.
// -------------------------------------------------------------------------
__global__ __launch_bounds__(256) void k_compute_v(
        const float* __restrict__ emb1, const float* __restrict__ w1,
        const float* __restrict__ b1,
        const float* __restrict__ emb2, const float* __restrict__ w2,
        const float* __restrict__ b2,
        double* __restrict__ V1d, double* __restrict__ V2d,
        float* __restrict__ V1s, float* __restrict__ V2Ts) {
    __shared__ alignas(16) float embS[64 * 64];
    __shared__ alignas(16) float wS[64 * 64];
    __shared__ float bS[64];
    __shared__ float CSf[64 * 65];     // padded f32 transpose buffer

    int bx    = blockIdx.x;
    int which = bx >> 8;
    int rem   = bx & 255;
    int k     = rem >> 6;
    int tile  = rem & 63;
    int n0    = tile * 64;

    const float* emb = which ? emb2 : emb1;
    const float* w   = which ? w2 : w1;
    const float* b   = which ? b2 : b1;

    int tid = threadIdx.x;
    const float* esrc = emb + ((size_t)k * NSUB + n0) * DIM;
    const float* wsrc = w + (size_t)k * DIM * DIM;
    for (int t = tid; t < 64 * 64; t += 256) { embS[t] = esrc[t]; wS[t] = wsrc[t]; }
    if (tid < 64) bS[tid] = b[k * 64 + tid];
    __syncthreads();

    int e    = tid & 63;
    int mrow = tid >> 6;

    double accs[16];
#pragma unroll
    for (int it = 0; it < 16; ++it) accs[it] = (double)bS[e];

    for (int dg = 0; dg < 16; ++dg) {
        double wv[4];
#pragma unroll
        for (int q = 0; q < 4; ++q) wv[q] = (double)wS[(dg * 4 + q) * 64 + e];
#pragma unroll
        for (int it = 0; it < 16; ++it) {
            float4 em = *(const float4*)&embS[(mrow * 16 + it) * 64 + dg * 4];
            accs[it] += (double)em.x * wv[0] + (double)em.y * wv[1]
                      + (double)em.z * wv[2] + (double)em.w * wv[3];
        }
    }

    if (which == 0) {
#pragma unroll
        for (int it = 0; it < 16; ++it) {
            size_t o = ((size_t)k * NSUB + n0 + mrow * 16 + it) * DIM + e;
            V1d[o] = accs[it];
            V1s[o] = (float)accs[it];
        }
    } else {
#pragma unroll
        for (int it = 0; it < 16; ++it) {
            int m = mrow * 16 + it;
            size_t o = ((size_t)k * NSUB + n0 + m) * DIM + e;
            V2d[o] = accs[it];
            CSf[m * 65 + e] = (float)accs[it];
        }
        __syncthreads();
        int m2 = tid & 63;
        int eg = tid >> 6;
#pragma unroll
        for (int it = 0; it < 16; ++it) {
            int e2 = eg * 16 + it;
            V2Ts[((size_t)k * DIM + e2) * NSUB + n0 + m2] = CSf[m2 * 65 + e2];
        }
    }
}

// -------------------------------------------------------------------------
// K2 (fast pass, f32): per-row top-24 candidate selection.
// grid 512 wgs x 256 thr (4 waves). wg owns 16 rows; wave owns 4 rows, all
// 8192 cols. B (V2Ts) double-buffered through LDS in [16 d][256 col] tiles
// shared by the wg's waves. Sorted top-24 list per row lives across lanes
// 0..23 as keys ((u64)f32bits << 13) | (8191 - col).
// -------------------------------------------------------------------------
__global__ __launch_bounds__(256) void k_select(const float* __restrict__ V1s,
                                                const float* __restrict__ V2Ts,
                                                int* __restrict__ cand) {
    __shared__ alignas(16) float As[2][16][64];    // 8 KB
    __shared__ alignas(16) float Bs[2][16][256];   // 32 KB

    int tid = threadIdx.x;
    int r0  = blockIdx.x * 16;
    int i   = r0 >> 12;
    int n0  = r0 & (NSUB - 1);

    // stage A (V1 f32 for the wg's 16 rows, both j variants)
    for (int t = tid; t < 2048; t += 256) {
        int j = t >> 10, rr = (t >> 6) & 15, d = t & 63;
        As[j][rr][d] = V1s[((size_t)(2 * i + j) * NSUB + n0 + rr) * DIM + d];
    }

    int l = tid & 63;
    int w = tid >> 6;
    int rbase = 4 * w;

    u64 lst[4], th[4];
#pragma unroll
    for (int rr = 0; rr < 4; ++rr) { lst[rr] = (l < LM) ? (u64)(l + 1) : 0; th[rr] = (u64)LM; }

    int sd = tid >> 6;              // staging: wave -> d-subrows
    int sc = (tid & 63) * 4;        // staging: col within 256-chunk

    float acc[4][4];
#pragma unroll
    for (int a = 0; a < 4; ++a)
#pragma unroll
        for (int c = 0; c < 4; ++c) acc[a][c] = 0.f;

    float4 nx[4];
    // tile t (0..127): j = t>>6, mc = (t>>2)&15, dt = t&3
    auto load_tile = [&](int t) {
        int j = t >> 6, mc = (t >> 2) & 15, dt = t & 3;
        const float* gp = V2Ts + ((size_t)((2 * i + j) * 64 + dt * 16)) * NSUB + mc * 256;
#pragma unroll
        for (int p = 0; p < 4; ++p)
            nx[p] = *(const float4*)&gp[(size_t)(p * 4 + sd) * NSUB + sc];
    };
    auto store_tile = [&](int b) {
#pragma unroll
        for (int p = 0; p < 4; ++p)
            *(float4*)&Bs[b][p * 4 + sd][sc] = nx[p];
    };

    load_tile(0);
    store_tile(0);
    __syncthreads();

    for (int t = 0; t < 128; ++t) {
        int j = t >> 6, mc = (t >> 2) & 15, dt = t & 3;
        if (t + 1 < 128) load_tile(t + 1);
        int bi = t & 1;
#pragma unroll
        for (int dg = 0; dg < 4; ++dg) {
            float4 bq[4];
#pragma unroll
            for (int q = 0; q < 4; ++q) bq[q] = *(const float4*)&Bs[bi][dg * 4 + q][l * 4];
#pragma unroll
            for (int rr = 0; rr < 4; ++rr) {
                float4 a4 = *(const float4*)&As[j][rbase + rr][dt * 16 + dg * 4];
                acc[rr][0] += a4.x * bq[0].x + a4.y * bq[1].x + a4.z * bq[2].x + a4.w * bq[3].x;
                acc[rr][1] += a4.x * bq[0].y + a4.y * bq[1].y + a4.z * bq[2].y + a4.w * bq[3].y;
                acc[rr][2] += a4.x * bq[0].z + a4.y * bq[1].z + a4.z * bq[2].z + a4.w * bq[3].z;
                acc[rr][3] += a4.x * bq[0].w + a4.y * bq[1].w + a4.z * bq[2].w + a4.w * bq[3].w;
            }
        }
        if (dt == 3) {
            int cb = j * NSUB + mc * 256;
#pragma unroll
            for (int rr = 0; rr < 4; ++rr) {
#pragma unroll
                for (int q = 0; q < 4; ++q) {
                    float a = acc[rr][q];
                    u64 cd = (a > 0.f)
                        ? ((((u64)__float_as_uint(a)) << 13) | (u64)(8191 - (cb + l * 4 + q)))
                        : 0ull;
                    while (true) {
                        u64 m = __ballot(cd > th[rr]);
                        if (!m) break;
                        int src = __ffsll((unsigned long long)m) - 1;
                        u64 kk = (u64)__shfl((long long)cd, src);
                        u64 e  = lst[rr];
                        u64 up = (u64)__shfl_up((long long)e, 1);
                        int pos = __popcll(__ballot(e > kk));
                        u64 ne = (l < pos) ? e : ((l == pos) ? kk : up);
                        if (l < LM) lst[rr] = ne;
                        th[rr] = (u64)__shfl((long long)lst[rr], LM - 1);
                        if (l == src) cd = 0;
                    }
                }
            }
#pragma unroll
            for (int a = 0; a < 4; ++a)
#pragma unroll
                for (int c = 0; c < 4; ++c) acc[a][c] = 0.f;
        }
        if (t + 1 < 128) store_tile((t + 1) & 1);
        __syncthreads();
    }

    if (l < LM) {
#pragma unroll
        for (int rr = 0; rr < 4; ++rr)
            cand[(size_t)(r0 + rbase + rr) * LM + l] = 8191 - (int)(lst[rr] & 0x1FFFull);
    }
}

// -------------------------------------------------------------------------
// K3 (refine, f64): recompute the 24 candidates' scores in f64 (same serial
// d-order as the round-1 passing kernel), rank, take top-20 + tanh.
// grid 2048 wgs x 256 (wave per row).
// -------------------------------------------------------------------------
__global__ __launch_bounds__(256) void k_refine(const double* __restrict__ V1d,
                                                const double* __restrict__ V2d,
                                                const int* __restrict__ cand,
                                                int* __restrict__ outIdx,
                                                float* __restrict__ outVal) {
    int l = threadIdx.x & 63, w = threadIdx.x >> 6;
    int row = blockIdx.x * 4 + w;
    int i = row >> 12, n = row & (NSUB - 1);

    int c = (l < LM) ? cand[(size_t)row * LM + l] : 0;
    int k = 2 * i + (c >> 12);
    int m = c & (NSUB - 1);

    double a = 0.0;
    const double* v1p = V1d + ((size_t)k * NSUB + n) * DIM;
    const double* v2p = V2d + ((size_t)k * NSUB + m) * DIM;
    for (int d = 0; d < 64; ++d) a += v1p[d] * v2p[d];

    double av = a > 0.0 ? a : 0.0;
    u64 key = (((u64)__double_as_longlong(av)) & ~0x1FFFull) | (u64)(8191 - c);
    if (l >= LM) key = 0;

    int rank = 0;
    for (int jj = 0; jj < LM; ++jj) {
        u64 kj = (u64)__shfl((long long)key, jj);
        rank += (kj > key || (kj == key && jj < l)) ? 1 : 0;
    }
    if (l < LM && rank < KTOP) {
        float val = (av > 0.0) ? (float)tanh(3.0 * av) : 0.0f;
        outIdx[(size_t)row * KTOP + rank] = c;
        outVal[(size_t)row * KTOP + rank] = val;
    }
}

// -------------------------------------------------------------------------
// K4: scatter survivors into the zeroed output.
// -------------------------------------------------------------------------
__global__ void k_scatter(const int* __restrict__ outIdx, const float* __restrict__ outVal,
                          float* __restrict__ out) {
    int t = blockIdx.x * 256 + threadIdx.x;
    if (t >= NROW * KTOP) return;
    int row = t / KTOP;
    int c = outIdx[t];
    out[(size_t)row * NROW + c] = outVal[t];
}

extern "C" void kernel_launch(void* const* d_in, const int* in_sizes, int n_in,
                              void* d_out, int out_size, void* d_ws, size_t ws_size,
                              hipStream_t stream) {
    // inputs: idx, emb1, emb2, w1, w2, b1, b2
    const float* emb1 = (const float*)d_in[1];
    const float* emb2 = (const float*)d_in[2];
    const float* w1   = (const float*)d_in[3];
    const float* w2   = (const float*)d_in[4];
    const float* b1   = (const float*)d_in[5];
    const float* b2   = (const float*)d_in[6];
    float* out = (float*)d_out;

    // V staging in the head of d_out (24 MB of 256 MB); consumed before memset.
    double* V1d = (double*)d_out;
    double* V2d = V1d + (size_t)4 * NSUB * DIM;                 // +8 MB
    float*  V1s = (float*)(V2d + (size_t)4 * NSUB * DIM);       // +8 MB
    float*  V2Ts = V1s + (size_t)4 * NSUB * DIM;                // +4 MB

    int*   candp  = (int*)d_ws;                                             // 768 KB
    int*   outIdx = (int*)((char*)d_ws + (size_t)NROW * LM * sizeof(int));  // 640 KB
    float* outVal = (float*)((char*)outIdx + (size_t)NROW * KTOP * sizeof(int));

    hipLaunchKernelGGL(k_compute_v, dim3(512), dim3(256), 0, stream,
                       emb1, w1, b1, emb2, w2, b2, V1d, V2d, V1s, V2Ts);
    hipLaunchKernelGGL(k_select, dim3(512), dim3(256), 0, stream, V1s, V2Ts, candp);
    hipLaunchKernelGGL(k_refine, dim3(2048), dim3(256), 0, stream,
                       V1d, V2d, candp, outIdx, outVal);
    hipMemsetAsync(d_out, 0, (size_t)out_size * sizeof(float), stream);
    hipLaunchKernelGGL(k_scatter, dim3((NROW * KTOP + 255) / 256), dim3(256), 0, stream,
                       outIdx, outVal, out);
}

// Round 3
// 542.445 us; speedup vs baseline: 1.3505x; 1.3505x over previous
//
#include <hip/hip_runtime.h>
#include <hip/hip_bf16.h>

#define NSUB 4096
#define DIM 64
#define NROW 8192
#define KTOP 20
#define LM 32          // candidate list length (margin over 20; bf16-safe)

typedef unsigned long long u64;
typedef __attribute__((ext_vector_type(8))) short bf16x8;   // 8 bf16 = 4 VGPRs
typedef __attribute__((ext_vector_type(4))) float f32x4;

// -------------------------------------------------------------------------
// K1: V[k] = emb[k] @ w[k] + b[k], f64 accumulate from f32 inputs.
// Emits f64 row-major (for exact refine) + bf16 row-major (for MFMA select).
// grid 512 (= 2 which * 4 k * 64 tiles), block 256.
// -------------------------------------------------------------------------
__global__ __launch_bounds__(256) void k_compute_v(
        const float* __restrict__ emb1, const float* __restrict__ w1,
        const float* __restrict__ b1,
        const float* __restrict__ emb2, const float* __restrict__ w2,
        const float* __restrict__ b2,
        double* __restrict__ V1d, double* __restrict__ V2d,
        unsigned short* __restrict__ V1b, unsigned short* __restrict__ V2b) {
    __shared__ alignas(16) float embS[64 * 64];
    __shared__ alignas(16) float wS[64 * 64];
    __shared__ float bS[64];

    int bx    = blockIdx.x;
    int which = bx >> 8;
    int rem   = bx & 255;
    int k     = rem >> 6;
    int tile  = rem & 63;
    int n0    = tile * 64;

    const float* emb = which ? emb2 : emb1;
    const float* w   = which ? w2 : w1;
    const float* b   = which ? b2 : b1;
    double* Vd = which ? V2d : V1d;
    unsigned short* Vb = which ? V2b : V1b;

    int tid = threadIdx.x;
    const float* esrc = emb + ((size_t)k * NSUB + n0) * DIM;
    const float* wsrc = w + (size_t)k * DIM * DIM;
    for (int t = tid; t < 64 * 64; t += 256) { embS[t] = esrc[t]; wS[t] = wsrc[t]; }
    if (tid < 64) bS[tid] = b[k * 64 + tid];
    __syncthreads();

    int e    = tid & 63;
    int mrow = tid >> 6;

    double accs[16];
#pragma unroll
    for (int it = 0; it < 16; ++it) accs[it] = (double)bS[e];

    for (int dg = 0; dg < 16; ++dg) {
        double wv[4];
#pragma unroll
        for (int q = 0; q < 4; ++q) wv[q] = (double)wS[(dg * 4 + q) * 64 + e];
#pragma unroll
        for (int it = 0; it < 16; ++it) {
            float4 em = *(const float4*)&embS[(mrow * 16 + it) * 64 + dg * 4];
            accs[it] += (double)em.x * wv[0] + (double)em.y * wv[1]
                      + (double)em.z * wv[2] + (double)em.w * wv[3];
        }
    }

#pragma unroll
    for (int it = 0; it < 16; ++it) {
        size_t o = ((size_t)k * NSUB + n0 + mrow * 16 + it) * DIM + e;
        Vd[o] = accs[it];
        __hip_bfloat16 h = __float2bfloat16((float)accs[it]);
        Vb[o] = *reinterpret_cast<unsigned short*>(&h);
    }
}

// -------------------------------------------------------------------------
// K2 (select, bf16 MFMA): per-row top-32 candidate cols.
// grid 512 wgs x 256 (4 waves). wg owns 16 rows; wave w owns cols
// [2048w, 2048w+2048), j = w>>1, kb = 2i+j. A/B frags load directly from
// global (row-major bf16 matches the 16x16x32 A/B operand layout:
// elem = row(lane&15), k = (lane>>4)*8 + 0..7, second frag +32).
// Per 64-col strip: 8 MFMAs -> C to LDS (stride 65, conflict-free) ->
// barrier -> wave w ballot-filters rows 4w..4w+3 across all 4 col-ranges
// into a lane-resident sorted top-32 (key = f32bits<<13 | (8191-col)).
// -------------------------------------------------------------------------
__global__ __launch_bounds__(256) void k_select(const unsigned short* __restrict__ V1b,
                                                const unsigned short* __restrict__ V2b,
                                                int* __restrict__ cand) {
    __shared__ float buf[2][4][16][65];   // 33280 B

    int tid = threadIdx.x;
    int l = tid & 63;
    int w = tid >> 6;
    int r0 = blockIdx.x * 16;
    int i = r0 >> 12;
    int n0 = r0 & (NSUB - 1);
    int kb = 2 * i + (w >> 1);

    // A fragments (16 rows x K=64), reused across all col-tiles
    const unsigned short* ap =
        V1b + ((size_t)kb * NSUB + n0 + (l & 15)) * DIM + ((l >> 4) * 8);
    bf16x8 a0 = *(const bf16x8*)ap;
    bf16x8 a1 = *(const bf16x8*)(ap + 32);

    const unsigned short* bbase =
        V2b + ((size_t)kb * NSUB + (w & 1) * 2048 + (l & 15)) * DIM + ((l >> 4) * 8);

    u64 lst[4], th[4];
#pragma unroll
    for (int rr = 0; rr < 4; ++rr) { lst[rr] = (l < LM) ? (u64)(LM - l) : 0; th[rr] = 1; }

    bf16x8 cur[8], nxt[8];
#pragma unroll
    for (int t = 0; t < 4; ++t)
#pragma unroll
        for (int f = 0; f < 2; ++f)
            cur[t * 2 + f] = *(const bf16x8*)(bbase + (size_t)(t * 16) * DIM + f * 32);

    for (int s = 0; s < 32; ++s) {
        if (s < 31) {
#pragma unroll
            for (int t = 0; t < 4; ++t)
#pragma unroll
                for (int f = 0; f < 2; ++f)
                    nxt[t * 2 + f] =
                        *(const bf16x8*)(bbase + (size_t)((s + 1) * 64 + t * 16) * DIM + f * 32);
        }

        int qrow = (l >> 4) * 4;
#pragma unroll
        for (int t = 0; t < 4; ++t) {
            f32x4 acc = {0.f, 0.f, 0.f, 0.f};
            acc = __builtin_amdgcn_mfma_f32_16x16x32_bf16(a0, cur[t * 2 + 0], acc, 0, 0, 0);
            acc = __builtin_amdgcn_mfma_f32_16x16x32_bf16(a1, cur[t * 2 + 1], acc, 0, 0, 0);
#pragma unroll
            for (int rg = 0; rg < 4; ++rg)
                buf[s & 1][w][qrow + rg][t * 16 + (l & 15)] = acc[rg];
        }
        __syncthreads();

#pragma unroll
        for (int rr = 0; rr < 4; ++rr) {
            int row = 4 * w + rr;
#pragma unroll
            for (int u = 0; u < 4; ++u) {
                float v = buf[s & 1][u][row][l];
                int c = u * 2048 + s * 64 + l;
                u64 cd = (v > 0.f)
                    ? ((((u64)__float_as_uint(v)) << 13) | (u64)(8191 - c))
                    : 0ull;
                while (true) {
                    u64 m = __ballot(cd > th[rr]);
                    if (!m) break;
                    int src = __ffsll((unsigned long long)m) - 1;
                    u64 kk = (u64)__shfl((long long)cd, src);
                    u64 e  = lst[rr];
                    u64 up = (u64)__shfl_up((long long)e, 1);
                    int pos = __popcll(__ballot(e > kk));
                    u64 ne = (l < pos) ? e : ((l == pos) ? kk : up);
                    if (l < LM) lst[rr] = ne;
                    th[rr] = (u64)__shfl((long long)lst[rr], LM - 1);
                    if (l == src) cd = 0;
                }
            }
        }
#pragma unroll
        for (int q = 0; q < 8; ++q) cur[q] = nxt[q];
    }

    if (l < LM) {
#pragma unroll
        for (int rr = 0; rr < 4; ++rr)
            cand[(size_t)(r0 + 4 * w + rr) * LM + l] = 8191 - (int)(lst[rr] & 0x1FFFull);
    }
}

// -------------------------------------------------------------------------
// K3 (refine, f64 exact): recompute the 32 candidates' scores (same serial
// d-order as the R1/R2 passing kernels), rank, write top-20 + tanh.
// 2 rows per wave (lanes 0..31 / 32..63). grid 1024 x 256.
// -------------------------------------------------------------------------
__global__ __launch_bounds__(256) void k_refine(const double* __restrict__ V1d,
                                                const double* __restrict__ V2d,
                                                const int* __restrict__ cand,
                                                int* __restrict__ outIdx,
                                                float* __restrict__ outVal) {
    int tid = threadIdx.x;
    int l = tid & 63, w = tid >> 6;
    int half = l >> 5, ls = l & 31;
    int row = blockIdx.x * 8 + w * 2 + half;
    int i = row >> 12, n = row & (NSUB - 1);

    int c = cand[(size_t)row * LM + ls];
    int k = 2 * i + (c >> 12);
    int m = c & (NSUB - 1);

    const double* v1p = V1d + ((size_t)k * NSUB + n) * DIM;
    const double* v2p = V2d + ((size_t)k * NSUB + m) * DIM;
    double a = 0.0;
    for (int d = 0; d < DIM; ++d) a += v1p[d] * v2p[d];

    double av = a > 0.0 ? a : 0.0;
    u64 key = (((u64)__double_as_longlong(av)) & ~0x1FFFull) | (u64)(8191 - c);

    int base = half * 32;
    int rank = 0;
    for (int jj = 0; jj < LM; ++jj) {
        u64 kj = (u64)__shfl((long long)key, base + jj);
        rank += (kj > key || (kj == key && jj < ls)) ? 1 : 0;
    }
    if (rank < KTOP) {
        float val = (av > 0.0) ? (float)tanh(3.0 * av) : 0.0f;
        outIdx[(size_t)row * KTOP + rank] = c;
        outVal[(size_t)row * KTOP + rank] = val;
    }
}

// -------------------------------------------------------------------------
// K4: fused zero + scatter. wg owns 4 contiguous rows (128 KB): vectorized
// zero stores, one barrier, then 80 survivor patches (L2-hot lines).
// grid 2048 x 256.
// -------------------------------------------------------------------------
__global__ __launch_bounds__(256) void k_write(const int* __restrict__ outIdx,
                                               const float* __restrict__ outVal,
                                               float* __restrict__ out) {
    int t = threadIdx.x;
    size_t base = (size_t)blockIdx.x * 4 * NROW;
    float4 z = {0.f, 0.f, 0.f, 0.f};
    float4* o4 = (float4*)(out + base);
#pragma unroll
    for (int it = 0; it < 32; ++it) o4[it * 256 + t] = z;
    __syncthreads();
    if (t < 4 * KTOP) {
        int row = blockIdx.x * 4 + t / KTOP;
        int c = outIdx[(size_t)blockIdx.x * 4 * KTOP + t];
        float v = outVal[(size_t)blockIdx.x * 4 * KTOP + t];
        out[(size_t)row * NROW + c] = v;
    }
}

extern "C" void kernel_launch(void* const* d_in, const int* in_sizes, int n_in,
                              void* d_out, int out_size, void* d_ws, size_t ws_size,
                              hipStream_t stream) {
    // inputs: idx, emb1, emb2, w1, w2, b1, b2
    const float* emb1 = (const float*)d_in[1];
    const float* emb2 = (const float*)d_in[2];
    const float* w1   = (const float*)d_in[3];
    const float* w2   = (const float*)d_in[4];
    const float* b1   = (const float*)d_in[5];
    const float* b2   = (const float*)d_in[6];
    float* out = (float*)d_out;

    // staging in the head of d_out (21 MB of 256 MB); fully consumed by
    // k_refine before k_write overwrites everything.
    char* p = (char*)d_out;
    double*         V1d = (double*)p;                                  // 8 MB
    double*         V2d = (double*)(p + (size_t)8 * 1024 * 1024);      // 8 MB
    unsigned short* V1b = (unsigned short*)(p + (size_t)16 * 1024 * 1024); // 2 MB
    unsigned short* V2b = (unsigned short*)(p + (size_t)18 * 1024 * 1024); // 2 MB
    int*            candp = (int*)(p + (size_t)20 * 1024 * 1024);      // 1 MB

    int*   outIdx = (int*)d_ws;                                        // 640 KB
    float* outVal = (float*)((char*)d_ws + (size_t)NROW * KTOP * sizeof(int));

    hipLaunchKernelGGL(k_compute_v, dim3(512), dim3(256), 0, stream,
                       emb1, w1, b1, emb2, w2, b2, V1d, V2d, V1b, V2b);
    hipLaunchKernelGGL(k_select, dim3(512), dim3(256), 0, stream, V1b, V2b, candp);
    hipLaunchKernelGGL(k_refine, dim3(1024), dim3(256), 0, stream,
                       V1d, V2d, candp, outIdx, outVal);
    hipLaunchKernelGGL(k_write, dim3(2048), dim3(256), 0, stream,
                       outIdx, outVal, out);
}

// Round 4
// 524.880 us; speedup vs baseline: 1.3957x; 1.0335x over previous
//
#include <hip/hip_runtime.h>
#include <hip/hip_bf16.h>

#define NSUB 4096
#define DIM 64
#define NROW 8192
#define KTOP 20
#define LM 24          // candidates per column-half (margin 4 over 20)

typedef unsigned long long u64;
typedef __attribute__((ext_vector_type(8))) short bf16x8;   // 8 bf16 = 4 VGPRs
typedef __attribute__((ext_vector_type(4))) float f32x4;

// -------------------------------------------------------------------------
// K1: V[k] = emb[k] @ w[k] + b[k], f64 accumulate from f32 inputs.
// Emits f64 row-major (exact refine) + bf16 row-major (MFMA select).
// grid 512 (= 2 which * 4 k * 64 tiles), block 256.
// -------------------------------------------------------------------------
__global__ __launch_bounds__(256) void k_compute_v(
        const float* __restrict__ emb1, const float* __restrict__ w1,
        const float* __restrict__ b1,
        const float* __restrict__ emb2, const float* __restrict__ w2,
        const float* __restrict__ b2,
        double* __restrict__ V1d, double* __restrict__ V2d,
        unsigned short* __restrict__ V1b, unsigned short* __restrict__ V2b) {
    __shared__ alignas(16) float embS[64 * 64];
    __shared__ alignas(16) float wS[64 * 64];
    __shared__ float bS[64];

    int bx    = blockIdx.x;
    int which = bx >> 8;
    int rem   = bx & 255;
    int k     = rem >> 6;
    int tile  = rem & 63;
    int n0    = tile * 64;

    const float* emb = which ? emb2 : emb1;
    const float* w   = which ? w2 : w1;
    const float* b   = which ? b2 : b1;
    double* Vd = which ? V2d : V1d;
    unsigned short* Vb = which ? V2b : V1b;

    int tid = threadIdx.x;
    const float* esrc = emb + ((size_t)k * NSUB + n0) * DIM;
    const float* wsrc = w + (size_t)k * DIM * DIM;
    for (int t = tid; t < 64 * 64; t += 256) { embS[t] = esrc[t]; wS[t] = wsrc[t]; }
    if (tid < 64) bS[tid] = b[k * 64 + tid];
    __syncthreads();

    int e    = tid & 63;
    int mrow = tid >> 6;

    double accs[16];
#pragma unroll
    for (int it = 0; it < 16; ++it) accs[it] = (double)bS[e];

    for (int dg = 0; dg < 16; ++dg) {
        double wv[4];
#pragma unroll
        for (int q = 0; q < 4; ++q) wv[q] = (double)wS[(dg * 4 + q) * 64 + e];
#pragma unroll
        for (int it = 0; it < 16; ++it) {
            float4 em = *(const float4*)&embS[(mrow * 16 + it) * 64 + dg * 4];
            accs[it] += (double)em.x * wv[0] + (double)em.y * wv[1]
                      + (double)em.z * wv[2] + (double)em.w * wv[3];
        }
    }

#pragma unroll
    for (int it = 0; it < 16; ++it) {
        size_t o = ((size_t)k * NSUB + n0 + mrow * 16 + it) * DIM + e;
        Vd[o] = accs[it];
        __hip_bfloat16 hv = __float2bfloat16((float)accs[it]);
        Vb[o] = *reinterpret_cast<unsigned short*>(&hv);
    }
}

// -------------------------------------------------------------------------
// K2 (select, bf16 MFMA): per-row, per-column-half top-24.
// grid 1024 (= 512 row-tiles x 2 col-halves), block 256 (4 waves).
// wg = 16 rows x 4096 cols (half h); wave w covers cols [w*1024,(w+1)*1024)
// of the half; kb = 2i+h. 16 strips of 64 cols; per strip: 8 MFMAs -> C to
// LDS (stride 72: bank-conflict-free 2-way) -> barrier -> wave w filters
// rows 4w..4w+3 across all 4 waves' bufs. Fast path: one predicate ballot
// per (rr,strip) vs float threshold snapshot; serialized insertion only on
// hit. List key = ((u64)f32bits << 13) | (8191 - col), lanes 0..23 sorted.
// -------------------------------------------------------------------------
__global__ __launch_bounds__(256) void k_select(const unsigned short* __restrict__ V1b,
                                                const unsigned short* __restrict__ V2b,
                                                int* __restrict__ cand) {
    __shared__ float buf[2][4][16][72];   // 36864 B -> 4 wg/CU

    int tid = threadIdx.x;
    int l = tid & 63;
    int w = tid >> 6;
    int bx = blockIdx.x;
    int r0 = (bx >> 1) * 16;
    int h  = bx & 1;
    int i  = r0 >> 12;
    int n0 = r0 & (NSUB - 1);
    int kb = 2 * i + h;

    // A fragments (16 rows x K=64), reused across all col-tiles
    const unsigned short* ap =
        V1b + ((size_t)kb * NSUB + n0 + (l & 15)) * DIM + ((l >> 4) * 8);
    bf16x8 a0 = *(const bf16x8*)ap;
    bf16x8 a1 = *(const bf16x8*)(ap + 32);

    const unsigned short* bbase =
        V2b + ((size_t)kb * NSUB + w * 1024 + (l & 15)) * DIM + ((l >> 4) * 8);

    u64 lst[4], th[4];
    float thf[4];
#pragma unroll
    for (int rr = 0; rr < 4; ++rr) {
        lst[rr] = (l < LM) ? (u64)(LM - l) : 0;
        th[rr] = 1;
        thf[rr] = 1e-38f;
    }

    int qrow = (l >> 4) * 4;

    for (int s = 0; s < 16; ++s) {
        int bi = s & 1;
#pragma unroll
        for (int t = 0; t < 4; ++t) {
            const unsigned short* bp = bbase + (size_t)(s * 64 + t * 16) * DIM;
            bf16x8 b0 = *(const bf16x8*)bp;
            bf16x8 b1 = *(const bf16x8*)(bp + 32);
            f32x4 acc = {0.f, 0.f, 0.f, 0.f};
            acc = __builtin_amdgcn_mfma_f32_16x16x32_bf16(a0, b0, acc, 0, 0, 0);
            acc = __builtin_amdgcn_mfma_f32_16x16x32_bf16(a1, b1, acc, 0, 0, 0);
#pragma unroll
            for (int rg = 0; rg < 4; ++rg)
                buf[bi][w][qrow + rg][t * 16 + (l & 15)] = acc[rg];
        }
        __syncthreads();

#pragma unroll
        for (int rr = 0; rr < 4; ++rr) {
            int row = 4 * w + rr;
            float v0 = buf[bi][0][row][l];
            float v1 = buf[bi][1][row][l];
            float v2 = buf[bi][2][row][l];
            float v3 = buf[bi][3][row][l];
            bool p = (v0 >= thf[rr]) || (v1 >= thf[rr]) ||
                     (v2 >= thf[rr]) || (v3 >= thf[rr]);
            if (__ballot(p)) {
                float vu[4] = {v0, v1, v2, v3};
#pragma unroll
                for (int u = 0; u < 4; ++u) {
                    float vv = vu[u];
                    int c = h * 4096 + u * 1024 + s * 64 + l;
                    u64 cd = (vv > 0.f)
                        ? ((((u64)__float_as_uint(vv)) << 13) | (u64)(8191 - c))
                        : 0ull;
                    while (true) {
                        u64 m = __ballot(cd > th[rr]);
                        if (!m) break;
                        int src = __ffsll((unsigned long long)m) - 1;
                        u64 kk = (u64)__shfl((long long)cd, src);
                        u64 e  = lst[rr];
                        u64 up = (u64)__shfl_up((long long)e, 1);
                        int pos = __popcll(__ballot(e > kk));
                        u64 ne = (l < pos) ? e : ((l == pos) ? kk : up);
                        if (l < LM) lst[rr] = ne;
                        th[rr] = (u64)__shfl((long long)lst[rr], LM - 1);
                        if (l == src) cd = 0;
                    }
                }
                thf[rr] = __uint_as_float((unsigned)(th[rr] >> 13));
            }
        }
    }

    if (l < LM) {
#pragma unroll
        for (int rr = 0; rr < 4; ++rr)
            cand[((size_t)(r0 + 4 * w + rr) * 2 + h) * LM + l] =
                8191 - (int)(lst[rr] & 0x1FFFull);
    }
}

// -------------------------------------------------------------------------
// K3 (refine, f64 exact): recompute the 48 candidates' scores (same serial
// d-order as all passing rounds), rank within the wave, write top-20 + tanh.
// One row per wave (lanes 0..47 hold candidates). grid 2048 x 256.
// -------------------------------------------------------------------------
__global__ __launch_bounds__(256) void k_refine(const double* __restrict__ V1d,
                                                const double* __restrict__ V2d,
                                                const int* __restrict__ cand,
                                                int* __restrict__ outIdx,
                                                float* __restrict__ outVal) {
    int tid = threadIdx.x;
    int l = tid & 63, w = tid >> 6;
    int row = blockIdx.x * 4 + w;
    int i = row >> 12, n = row & (NSUB - 1);

    int c = 0;
    if (l < 48) {
        int hh = l / LM, j = l % LM;
        c = cand[((size_t)row * 2 + hh) * LM + j];
    }
    int k = 2 * i + (c >> 12);
    int m = c & (NSUB - 1);

    const double* v1p = V1d + ((size_t)k * NSUB + n) * DIM;
    const double* v2p = V2d + ((size_t)k * NSUB + m) * DIM;
    double a = 0.0;
    for (int d = 0; d < DIM; ++d) a += v1p[d] * v2p[d];

    double av = a > 0.0 ? a : 0.0;
    u64 key = (((u64)__double_as_longlong(av)) & ~0x1FFFull) | (u64)(8191 - c);
    if (l >= 48) key = 0;

    int rank = 0;
    for (int jj = 0; jj < 48; ++jj) {
        u64 kj = (u64)__shfl((long long)key, jj);
        rank += (kj > key || (kj == key && jj < l)) ? 1 : 0;
    }
    if (l < 48 && rank < KTOP) {
        float val = (av > 0.0) ? (float)tanh(3.0 * av) : 0.0f;
        outIdx[(size_t)row * KTOP + rank] = c;
        outVal[(size_t)row * KTOP + rank] = val;
    }
}

// -------------------------------------------------------------------------
// K4: fused zero + scatter. wg owns 4 contiguous rows (128 KB).
// grid 2048 x 256.
// -------------------------------------------------------------------------
__global__ __launch_bounds__(256) void k_write(const int* __restrict__ outIdx,
                                               const float* __restrict__ outVal,
                                               float* __restrict__ out) {
    int t = threadIdx.x;
    size_t base = (size_t)blockIdx.x * 4 * NROW;
    float4 z = {0.f, 0.f, 0.f, 0.f};
    float4* o4 = (float4*)(out + base);
#pragma unroll
    for (int it = 0; it < 32; ++it) o4[it * 256 + t] = z;
    __syncthreads();
    if (t < 4 * KTOP) {
        int row = blockIdx.x * 4 + t / KTOP;
        int c = outIdx[(size_t)blockIdx.x * 4 * KTOP + t];
        float v = outVal[(size_t)blockIdx.x * 4 * KTOP + t];
        out[(size_t)row * NROW + c] = v;
    }
}

extern "C" void kernel_launch(void* const* d_in, const int* in_sizes, int n_in,
                              void* d_out, int out_size, void* d_ws, size_t ws_size,
                              hipStream_t stream) {
    // inputs: idx, emb1, emb2, w1, w2, b1, b2
    const float* emb1 = (const float*)d_in[1];
    const float* emb2 = (const float*)d_in[2];
    const float* w1   = (const float*)d_in[3];
    const float* w2   = (const float*)d_in[4];
    const float* b1   = (const float*)d_in[5];
    const float* b2   = (const float*)d_in[6];
    float* out = (float*)d_out;

    // staging in the head of d_out (22 MB of 256 MB); fully consumed by
    // k_refine before k_write overwrites everything.
    char* p = (char*)d_out;
    double*         V1d = (double*)p;                                      // 8 MB
    double*         V2d = (double*)(p + (size_t)8 * 1024 * 1024);          // 8 MB
    unsigned short* V1b = (unsigned short*)(p + (size_t)16 * 1024 * 1024); // 2 MB
    unsigned short* V2b = (unsigned short*)(p + (size_t)18 * 1024 * 1024); // 2 MB
    int*            candp = (int*)(p + (size_t)20 * 1024 * 1024);          // 1.5 MB

    int*   outIdx = (int*)d_ws;                                            // 640 KB
    float* outVal = (float*)((char*)d_ws + (size_t)NROW * KTOP * sizeof(int));

    hipLaunchKernelGGL(k_compute_v, dim3(512), dim3(256), 0, stream,
                       emb1, w1, b1, emb2, w2, b2, V1d, V2d, V1b, V2b);
    hipLaunchKernelGGL(k_select, dim3(1024), dim3(256), 0, stream, V1b, V2b, candp);
    hipLaunchKernelGGL(k_refine, dim3(2048), dim3(256), 0, stream,
                       V1d, V2d, candp, outIdx, outVal);
    hipLaunchKernelGGL(k_write, dim3(2048), dim3(256), 0, stream,
                       outIdx, outVal, out);
}

// Round 5
// 478.304 us; speedup vs baseline: 1.5316x; 1.0974x over previous
//
#include <hip/hip_runtime.h>
#include <hip/hip_bf16.h>

#define NSUB 4096
#define DIM 64
#define NROW 8192
#define KTOP 20
#define CAND 64        // max survivors per row in filter pass

typedef unsigned long long u64;
typedef __attribute__((ext_vector_type(8))) short bf16x8;   // 8 bf16 = 4 VGPRs
typedef __attribute__((ext_vector_type(4))) float f32x4;

__device__ __forceinline__ unsigned umax(unsigned a, unsigned b) { return a > b ? a : b; }
__device__ __forceinline__ unsigned umin(unsigned a, unsigned b) { return a < b ? a : b; }

// -------------------------------------------------------------------------
// K1: V[k] = emb[k] @ w[k] + b[k], f64 accumulate from f32 inputs.
// Emits f64 row-major (exact refine) + bf16 row-major (MFMA passes).
// grid 512, block 256. (unchanged from R3/R4 — verified)
// -------------------------------------------------------------------------
__global__ __launch_bounds__(256) void k_compute_v(
        const float* __restrict__ emb1, const float* __restrict__ w1,
        const float* __restrict__ b1,
        const float* __restrict__ emb2, const float* __restrict__ w2,
        const float* __restrict__ b2,
        double* __restrict__ V1d, double* __restrict__ V2d,
        unsigned short* __restrict__ V1b, unsigned short* __restrict__ V2b) {
    __shared__ alignas(16) float embS[64 * 64];
    __shared__ alignas(16) float wS[64 * 64];
    __shared__ float bS[64];

    int bx    = blockIdx.x;
    int which = bx >> 8;
    int rem   = bx & 255;
    int k     = rem >> 6;
    int tile  = rem & 63;
    int n0    = tile * 64;

    const float* emb = which ? emb2 : emb1;
    const float* w   = which ? w2 : w1;
    const float* b   = which ? b2 : b1;
    double* Vd = which ? V2d : V1d;
    unsigned short* Vb = which ? V2b : V1b;

    int tid = threadIdx.x;
    const float* esrc = emb + ((size_t)k * NSUB + n0) * DIM;
    const float* wsrc = w + (size_t)k * DIM * DIM;
    for (int t = tid; t < 64 * 64; t += 256) { embS[t] = esrc[t]; wS[t] = wsrc[t]; }
    if (tid < 64) bS[tid] = b[k * 64 + tid];
    __syncthreads();

    int e    = tid & 63;
    int mrow = tid >> 6;

    double accs[16];
#pragma unroll
    for (int it = 0; it < 16; ++it) accs[it] = (double)bS[e];

    for (int dg = 0; dg < 16; ++dg) {
        double wv[4];
#pragma unroll
        for (int q = 0; q < 4; ++q) wv[q] = (double)wS[(dg * 4 + q) * 64 + e];
#pragma unroll
        for (int it = 0; it < 16; ++it) {
            float4 em = *(const float4*)&embS[(mrow * 16 + it) * 64 + dg * 4];
            accs[it] += (double)em.x * wv[0] + (double)em.y * wv[1]
                      + (double)em.z * wv[2] + (double)em.w * wv[3];
        }
    }

#pragma unroll
    for (int it = 0; it < 16; ++it) {
        size_t o = ((size_t)k * NSUB + n0 + mrow * 16 + it) * DIM + e;
        Vd[o] = accs[it];
        __hip_bfloat16 hv = __float2bfloat16((float)accs[it]);
        Vb[o] = *reinterpret_cast<unsigned short*>(&hv);
    }
}

// -------------------------------------------------------------------------
// K2 (stage1): MFMA all scores; per (row, 256-col block) top-2 values,
// entirely in registers (running per-lane top-2, butterfly over the 16
// lanes sharing each C-row every 4 strips). No LDS, no barriers, no
// serialized insertion. grid 1024 (512 row-tiles x 2 halves), block 256.
// Output S1[row][32 blocks][2] f32-bits (keys = bits of max(v,0)).
// -------------------------------------------------------------------------
__global__ __launch_bounds__(256) void k_stage1(const unsigned short* __restrict__ V1b,
                                                const unsigned short* __restrict__ V2b,
                                                unsigned int* __restrict__ S1) {
    int tid = threadIdx.x;
    int l = tid & 63;
    int w = tid >> 6;
    int bx = blockIdx.x;
    int r0 = (bx >> 1) * 16;
    int h  = bx & 1;
    int i  = r0 >> 12;
    int n0 = r0 & (NSUB - 1);
    int kb = 2 * i + h;

    const unsigned short* ap =
        V1b + ((size_t)kb * NSUB + n0 + (l & 15)) * DIM + ((l >> 4) * 8);
    bf16x8 a0 = *(const bf16x8*)ap;
    bf16x8 a1 = *(const bf16x8*)(ap + 32);

    const unsigned short* bbase =
        V2b + ((size_t)kb * NSUB + w * 1024 + (l & 15)) * DIM + ((l >> 4) * 8);

    unsigned m1[4] = {0, 0, 0, 0}, m2[4] = {0, 0, 0, 0};
    int q = l >> 4;

    for (int s = 0; s < 16; ++s) {
#pragma unroll
        for (int t = 0; t < 4; ++t) {
            const unsigned short* bp = bbase + (size_t)(s * 64 + t * 16) * DIM;
            bf16x8 b0 = *(const bf16x8*)bp;
            bf16x8 b1v = *(const bf16x8*)(bp + 32);
            f32x4 acc = {0.f, 0.f, 0.f, 0.f};
            acc = __builtin_amdgcn_mfma_f32_16x16x32_bf16(a0, b0, acc, 0, 0, 0);
            acc = __builtin_amdgcn_mfma_f32_16x16x32_bf16(a1, b1v, acc, 0, 0, 0);
#pragma unroll
            for (int r = 0; r < 4; ++r) {
                unsigned key = __float_as_uint(fmaxf(acc[r], 0.f));
                m2[r] = umax(m2[r], umin(m1[r], key));
                m1[r] = umax(m1[r], key);
            }
        }
        if ((s & 3) == 3) {
            // butterfly top-2 merge over the 16 lanes sharing each row
#pragma unroll
            for (int st = 1; st <= 8; st <<= 1) {
#pragma unroll
                for (int r = 0; r < 4; ++r) {
                    unsigned o1 = (unsigned)__shfl_xor((int)m1[r], st);
                    unsigned o2 = (unsigned)__shfl_xor((int)m2[r], st);
                    unsigned nm1 = umax(m1[r], o1);
                    unsigned nm2 = umax(umin(m1[r], o1), umax(m2[r], o2));
                    m1[r] = nm1; m2[r] = nm2;
                }
            }
            if ((l & 15) == 0) {
                int gblk = h * 16 + w * 4 + (s >> 2);
#pragma unroll
                for (int r = 0; r < 4; ++r) {
                    int rowg = r0 + q * 4 + r;
                    uint2 v; v.x = m1[r]; v.y = m2[r];
                    *(uint2*)&S1[(size_t)rowg * 64 + gblk * 2] = v;
                }
            }
#pragma unroll
            for (int r = 0; r < 4; ++r) { m1[r] = 0; m2[r] = 0; }
        }
    }
}

// -------------------------------------------------------------------------
// K3 (thresh): per row, 20th largest of the 64 block-top-2 keys (bitonic
// sort in one wave), minus safety margin -> float threshold Lth[row].
// grid 2048 x 256 (wave per row).
// -------------------------------------------------------------------------
__global__ __launch_bounds__(256) void k_thresh(const unsigned int* __restrict__ S1,
                                                float* __restrict__ Lth) {
    int tid = threadIdx.x;
    int l = tid & 63, w = tid >> 6;
    int row = blockIdx.x * 4 + w;
    unsigned key = S1[(size_t)row * 64 + l];
#pragma unroll
    for (int k = 2; k <= 64; k <<= 1) {
#pragma unroll
        for (int j = k >> 1; j > 0; j >>= 1) {
            unsigned other = (unsigned)__shfl_xor((int)key, j);
            int ixj = l ^ j;
            bool up = ((l & k) == 0);
            bool keepMax = ((l > ixj) == up);
            key = keepMax ? umax(key, other) : umin(key, other);
        }
    }
    // ascending order; 20th largest is at lane 44
    if (l == 44) Lth[row] = fmaxf(__uint_as_float(key) - 0.006f, 1e-30f);
}

// -------------------------------------------------------------------------
// K4 (filter): recompute MFMA scores; append every value >= Lth[row] to the
// row's candidate list via global atomic (~27/row expected). No LDS C
// round-trip, no barriers in the loop. grid 1024 x 256.
// -------------------------------------------------------------------------
__global__ __launch_bounds__(256) void k_filter(const unsigned short* __restrict__ V1b,
                                                const unsigned short* __restrict__ V2b,
                                                const float* __restrict__ Lth,
                                                unsigned int* __restrict__ cnt,
                                                int* __restrict__ colsG) {
    __shared__ float Lsh[16];
    int tid = threadIdx.x;
    int l = tid & 63;
    int w = tid >> 6;
    int bx = blockIdx.x;
    int r0 = (bx >> 1) * 16;
    int h  = bx & 1;
    int i  = r0 >> 12;
    int n0 = r0 & (NSUB - 1);
    int kb = 2 * i + h;

    if (tid < 16) Lsh[tid] = Lth[r0 + tid];
    __syncthreads();

    const unsigned short* ap =
        V1b + ((size_t)kb * NSUB + n0 + (l & 15)) * DIM + ((l >> 4) * 8);
    bf16x8 a0 = *(const bf16x8*)ap;
    bf16x8 a1 = *(const bf16x8*)(ap + 32);

    const unsigned short* bbase =
        V2b + ((size_t)kb * NSUB + w * 1024 + (l & 15)) * DIM + ((l >> 4) * 8);

    int q = l >> 4;
    float Lr[4];
#pragma unroll
    for (int r = 0; r < 4; ++r) Lr[r] = Lsh[q * 4 + r];

    for (int s = 0; s < 16; ++s) {
#pragma unroll
        for (int t = 0; t < 4; ++t) {
            const unsigned short* bp = bbase + (size_t)(s * 64 + t * 16) * DIM;
            bf16x8 b0 = *(const bf16x8*)bp;
            bf16x8 b1v = *(const bf16x8*)(bp + 32);
            f32x4 acc = {0.f, 0.f, 0.f, 0.f};
            acc = __builtin_amdgcn_mfma_f32_16x16x32_bf16(a0, b0, acc, 0, 0, 0);
            acc = __builtin_amdgcn_mfma_f32_16x16x32_bf16(a1, b1v, acc, 0, 0, 0);
            int c = h * 4096 + w * 1024 + s * 64 + t * 16 + (l & 15);
#pragma unroll
            for (int r = 0; r < 4; ++r) {
                if (acc[r] >= Lr[r]) {
                    int rowg = r0 + q * 4 + r;
                    unsigned pos = atomicAdd(&cnt[rowg], 1u);
                    if (pos < CAND) colsG[(size_t)rowg * CAND + pos] = c;
                }
            }
        }
    }
}

// -------------------------------------------------------------------------
// K5 (refine, f64 exact): recompute candidates' scores (same serial d-order
// as all passing rounds), rank by (f64 value, lower-col) key, write
// top-20 + tanh. One wave per row. grid 2048 x 256.
// -------------------------------------------------------------------------
__global__ __launch_bounds__(256) void k_refine(const double* __restrict__ V1d,
                                                const double* __restrict__ V2d,
                                                const unsigned int* __restrict__ cnt,
                                                const int* __restrict__ colsG,
                                                int* __restrict__ outIdx,
                                                float* __restrict__ outVal) {
    int tid = threadIdx.x;
    int l = tid & 63, w = tid >> 6;
    int row = blockIdx.x * 4 + w;
    int i = row >> 12, n = row & (NSUB - 1);

    unsigned cn = cnt[row];
    if (cn > CAND) cn = CAND;
    bool valid = (unsigned)l < cn;
    int c = valid ? colsG[(size_t)row * CAND + l] : 0;
    int k = 2 * i + (c >> 12);
    int m = c & (NSUB - 1);

    const double* v1p = V1d + ((size_t)k * NSUB + n) * DIM;
    const double* v2p = V2d + ((size_t)k * NSUB + m) * DIM;
    double a = 0.0;
    for (int d = 0; d < DIM; ++d) a += v1p[d] * v2p[d];

    double av = a > 0.0 ? a : 0.0;
    u64 key = (((u64)__double_as_longlong(av)) & ~0x1FFFull) | (u64)(8191 - c);
    if (!valid) key = 0;

    int rank = 0;
    for (int jj = 0; jj < 64; ++jj) {
        u64 kj = (u64)__shfl((long long)key, jj);
        rank += (kj > key || (kj == key && jj < l)) ? 1 : 0;
    }
    if (valid && rank < KTOP) {
        float val = (av > 0.0) ? (float)tanh(3.0 * av) : 0.0f;
        outIdx[(size_t)row * KTOP + rank] = c;
        outVal[(size_t)row * KTOP + rank] = val;
    }
}

// -------------------------------------------------------------------------
// K6: fused zero + scatter. wg owns 4 contiguous rows (128 KB).
// grid 2048 x 256. (unchanged from R4 — verified)
// -------------------------------------------------------------------------
__global__ __launch_bounds__(256) void k_write(const int* __restrict__ outIdx,
                                               const float* __restrict__ outVal,
                                               float* __restrict__ out) {
    int t = threadIdx.x;
    size_t base = (size_t)blockIdx.x * 4 * NROW;
    float4 z = {0.f, 0.f, 0.f, 0.f};
    float4* o4 = (float4*)(out + base);
#pragma unroll
    for (int it = 0; it < 32; ++it) o4[it * 256 + t] = z;
    __syncthreads();
    if (t < 4 * KTOP) {
        int row = blockIdx.x * 4 + t / KTOP;
        int c = outIdx[(size_t)blockIdx.x * 4 * KTOP + t];
        float v = outVal[(size_t)blockIdx.x * 4 * KTOP + t];
        out[(size_t)row * NROW + c] = v;
    }
}

extern "C" void kernel_launch(void* const* d_in, const int* in_sizes, int n_in,
                              void* d_out, int out_size, void* d_ws, size_t ws_size,
                              hipStream_t stream) {
    // inputs: idx, emb1, emb2, w1, w2, b1, b2
    const float* emb1 = (const float*)d_in[1];
    const float* emb2 = (const float*)d_in[2];
    const float* w1   = (const float*)d_in[3];
    const float* w2   = (const float*)d_in[4];
    const float* b1   = (const float*)d_in[5];
    const float* b2   = (const float*)d_in[6];
    float* out = (float*)d_out;

    // staging in the head of d_out (24 MB of 256 MB); fully consumed by
    // k_refine before k_write overwrites everything.
    char* p = (char*)d_out;
    double*         V1d   = (double*)p;                                      // 0..8 MB
    double*         V2d   = (double*)(p + (size_t)8 * 1024 * 1024);          // 8..16 MB
    unsigned short* V1b   = (unsigned short*)(p + (size_t)16 * 1024 * 1024); // 16..18 MB
    unsigned short* V2b   = (unsigned short*)(p + (size_t)18 * 1024 * 1024); // 18..20 MB
    unsigned int*   S1    = (unsigned int*)(p + (size_t)20 * 1024 * 1024);   // 20..22 MB
    int*            colsG = (int*)(p + (size_t)22 * 1024 * 1024);            // 22..24 MB

    // workspace: outIdx 640K, outVal 640K, cnt 32K, Lth 32K  (ws >= 2 MB per R2)
    int*          outIdx = (int*)d_ws;
    float*        outVal = (float*)((char*)d_ws + (size_t)NROW * KTOP * sizeof(int));
    unsigned int* cntp   = (unsigned int*)((char*)d_ws + (size_t)2 * NROW * KTOP * sizeof(int));
    float*        Lth    = (float*)((char*)cntp + (size_t)NROW * sizeof(unsigned int));

    hipLaunchKernelGGL(k_compute_v, dim3(512), dim3(256), 0, stream,
                       emb1, w1, b1, emb2, w2, b2, V1d, V2d, V1b, V2b);
    hipMemsetAsync(cntp, 0, (size_t)NROW * sizeof(unsigned int), stream);
    hipLaunchKernelGGL(k_stage1, dim3(1024), dim3(256), 0, stream, V1b, V2b, S1);
    hipLaunchKernelGGL(k_thresh, dim3(2048), dim3(256), 0, stream, S1, Lth);
    hipLaunchKernelGGL(k_filter, dim3(1024), dim3(256), 0, stream, V1b, V2b, Lth, cntp, colsG);
    hipLaunchKernelGGL(k_refine, dim3(2048), dim3(256), 0, stream,
                       V1d, V2d, cntp, colsG, outIdx, outVal);
    hipLaunchKernelGGL(k_write, dim3(2048), dim3(256), 0, stream,
                       outIdx, outVal, out);
}